// Round 10
// baseline (301.059 us; speedup 1.0000x reference)
//
#include <hip/hip_runtime.h>
#include <stdint.h>

// Problem constants: B=4, N=32768, K=16, nqueries=2048, stride=16.
//
// Two-kernel scheme:
//  1) repack_kernel: xyz -> workspace float4 {x, y, z, |p|^2}  (2 MB, L2-res)
//  2) knn1: ONE query per wave (8192 waves = 8/SIMD = occupancy cap tier).
//     Gate per point: 3 fma + 1 cmp off the precomputed |p|^2:
//       t = |p|^2 - 2 p.q   vs   th = tau - |q|^2 + margin.
//     Insert work per query is unchanged vs the 2q/wave kernel (no
//     duplication -- the R7 mistake). Conservative gate (margin 5e-4 >>
//     4e-5 fp-error bound); accepted lanes re-verified with the EXACT
//     numpy-ordered distance, so results stay bit-exact.
// Fallback: if ws_size < 2 MB, launch the proven R9 2q/wave kernel.
#define NPTS  32768
#define NQ    2048
#define KNN   16
#define NB    4
#define GATE_MARGIN 5e-4f

__device__ __forceinline__ int dpp_shr1_i(int x) {
    // row_shr:1 within 16-lane rows; row-start lane keeps old (bound_ctrl=0)
    return __builtin_amdgcn_update_dpp(x, x, 0x111, 0xf, 0xf, false);
}
__device__ __forceinline__ float dpp_shr1_f(float x) {
    return __int_as_float(dpp_shr1_i(__float_as_int(x)));
}
__device__ __forceinline__ float readlane_f(float x, int l) {
    return __int_as_float(__builtin_amdgcn_readlane(__float_as_int(x), l));
}

// Exact distributed top-16 for query T: sorted list (ascending by (dist,idx))
// in lanes 16T..16T+15; lane 16T+15 holds the exact threshold tau.
// d is the EXACT numpy distance. th = tau + qnm is the conservative
// dot-product-gate threshold (qnm = -|q|^2 + margin).
template <int T>
__device__ __forceinline__ void insert_all(float d, int p, int lane,
                                           float& ld, int& li, float& tau,
                                           float& th, float qnm)
{
    unsigned long long rem = __ballot(d <= tau);
    while (rem) {
        const int srcl = __ffsll(rem) - 1;           // wave-uniform
        const float wd = readlane_f(d, srcl);
        const int   wi = __builtin_amdgcn_readlane(p, srcl);
        const bool less = (ld < wd) || (ld == wd && li < wi);
        const unsigned long long lm = __ballot(less);
        const int pos = __popc((unsigned)((lm >> (16 * T)) & 0xffffull));
        const float pld = dpp_shr1_f(ld);
        const int   pli = dpp_shr1_i(li);
        if ((lane >> 4) == T) {
            const int gl = lane & 15;
            if (gl == pos)      { ld = wd;  li = wi;  }
            else if (gl > pos)  { ld = pld; li = pli; }
        }
        tau = readlane_f(ld, 16 * T + 15);
        th  = tau + qnm;                             // gate threshold update
        rem &= rem - 1;
        if (rem) rem &= __ballot(d <= tau);          // re-gate survivors (exact)
    }
}

// ---------------- pre-pass: {x,y,z} -> {x,y,z,|p|^2} ----------------
__global__ __launch_bounds__(256) void repack_kernel(const float* __restrict__ xyz,
                                                     float4* __restrict__ ws)
{
    const int i = blockIdx.x * 256 + threadIdx.x;    // 4-point group, [0,32768)
    const float4* src = (const float4*)xyz + 3 * (size_t)i;
    const float4 c0 = src[0], c1 = src[1], c2 = src[2];
    float px[4], py[4], pz[4];
    px[0] = c0.x; py[0] = c0.y; pz[0] = c0.z;
    px[1] = c0.w; py[1] = c1.x; pz[1] = c1.y;
    px[2] = c1.z; py[2] = c1.w; pz[2] = c2.x;
    px[3] = c2.y; py[3] = c2.z; pz[3] = c2.w;
    float4* dst = ws + 4 * (size_t)i;
    #pragma unroll
    for (int t = 0; t < 4; ++t) {
        const float s = __fmaf_rn(pz[t], pz[t],
                          __fmaf_rn(py[t], py[t], __fmul_rn(px[t], px[t])));
        dst[t] = make_float4(px[t], py[t], pz[t], s);
    }
}

// ---------------- main kernel: 1 query per wave ----------------
#define BLOCKA 256
#define WPBA   4
#define PPLA   4
#define ITERSA (NPTS / (64 * PPLA))   // 128

__device__ __forceinline__ void load4(float4 dst[4], const float4* p) {
    #pragma unroll
    for (int t = 0; t < 4; ++t) dst[t] = p[t];
}

__device__ __forceinline__ void stepA(const float4 c[4], int pb, int lane,
                                      float m2x, float m2y, float m2z,
                                      float qx, float qy, float qz,
                                      float& ld, int& li,
                                      float& tau, float& th, float qnm)
{
    unsigned long long m[4], any = 0;
    #pragma unroll
    for (int j = 0; j < PPLA; ++j) {                 // 3 fma + 1 cmp per point
        float t = __fmaf_rn(c[j].x, m2x, c[j].w);
        t = __fmaf_rn(c[j].y, m2y, t);
        t = __fmaf_rn(c[j].z, m2z, t);
        m[j] = __ballot(t <= th);
        any |= m[j];
    }
    if (any) {
        #pragma unroll
        for (int j = 0; j < PPLA; ++j) {
            if (m[j]) {                              // exact numpy distance
                const float dx = __fadd_rn(c[j].x, -qx);
                const float dy = __fadd_rn(c[j].y, -qy);
                const float dz = __fadd_rn(c[j].z, -qz);
                const float d  = __fadd_rn(
                    __fadd_rn(__fmul_rn(dx, dx), __fmul_rn(dy, dy)),
                    __fmul_rn(dz, dz));
                insert_all<0>(d, pb + j, lane, ld, li, tau, th, qnm);
            }
        }
    }
}

// 2048 blocks x 4 waves = 8192 waves; natural VGPR ~55 (<=64) -> 8/SIMD.
__global__ __launch_bounds__(BLOCKA) void knn1(const float4* __restrict__ wsp,
                                               float* __restrict__ out_idx,
                                               float* __restrict__ out_pts)
{
    const int tid  = threadIdx.x;
    const int lane = tid & 63;
    const int wv   = tid >> 6;
    const int w    = blockIdx.x * WPBA + wv;         // wave id in [0, 8192)
    const int b    = w >> 11;
    const int qi   = w & 2047;                       // query id within batch
    const float4* pbase = wsp + (size_t)b * NPTS;

    const float4 qv = pbase[qi << 4];                // stride-16 subsample
    const float qx = qv.x, qy = qv.y, qz = qv.z;
    const float m2x = -2.0f * qx, m2y = -2.0f * qy, m2z = -2.0f * qz;
    const float qnm = -qv.w + GATE_MARGIN;           // |q|^2 free from repack

    const int g = b * NQ + qi;
    if (lane == 0) {
        out_pts[3 * g + 0] = qx;
        out_pts[3 * g + 1] = qy;
        out_pts[3 * g + 2] = qz;
    }

    float ld = __builtin_inff();  int li = 0x7fffffff;
    float tau = __builtin_inff(), th = __builtin_inff();

    // Lane's stream: 4 consecutive points (4 float4) per iteration.
    const float4* lp = pbase + 4 * lane;

    float4 A[4], Bf[4];
    load4(A, lp);                                    // prologue
    for (int k = 0; k < ITERSA; k += 2) {            // double-buffered pipeline
        load4(Bf, lp + 256);                         // prefetch iter k+1
        stepA(A, (k << 8) + 4 * lane, lane, m2x, m2y, m2z,
              qx, qy, qz, ld, li, tau, th, qnm);
        if (k + 2 < ITERSA)
            load4(A, lp + 512);                      // prefetch iter k+2
        stepA(Bf, ((k + 1) << 8) + 4 * lane, lane, m2x, m2y, m2z,
              qx, qy, qz, ld, li, tau, th, qnm);
        lp += 512;
    }

    if (lane < KNN) {
        out_idx[(size_t)g * KNN + lane] = (float)li;
    }
}

// ---------------- fallback: proven R9 kernel (2 queries/wave) ----------------
#define BLOCK 256
#define WPB   4
#define PPL   8
#define ITERS (NPTS / (64 * PPL))   // 64

__device__ __forceinline__ void load6(float4 dst[6], const float4* p) {
    #pragma unroll
    for (int t = 0; t < 6; ++t) dst[t] = p[t];
}

__device__ __forceinline__ void step2(const float4 c[6], int pb, int lane,
                                      float m2x0, float m2y0, float m2z0,
                                      float m2x1, float m2y1, float m2z1,
                                      float qx0, float qy0, float qz0,
                                      float qx1, float qy1, float qz1,
                                      float& ld, int& li,
                                      float& tau0, float& tau1,
                                      float& th0, float& th1,
                                      float qnm0, float qnm1)
{
    float px[PPL], py[PPL], pz[PPL];
    px[0] = c[0].x; py[0] = c[0].y; pz[0] = c[0].z;
    px[1] = c[0].w; py[1] = c[1].x; pz[1] = c[1].y;
    px[2] = c[1].z; py[2] = c[1].w; pz[2] = c[2].x;
    px[3] = c[2].y; py[3] = c[2].z; pz[3] = c[2].w;
    px[4] = c[3].x; py[4] = c[3].y; pz[4] = c[3].z;
    px[5] = c[3].w; py[5] = c[4].x; pz[5] = c[4].y;
    px[6] = c[4].z; py[6] = c[4].w; pz[6] = c[5].x;
    px[7] = c[5].y; py[7] = c[5].z; pz[7] = c[5].w;

    unsigned long long m0[PPL], m1[PPL], any = 0;
    #pragma unroll
    for (int j = 0; j < PPL; ++j) {
        const float s = __fmaf_rn(pz[j], pz[j],
                          __fmaf_rn(py[j], py[j], __fmul_rn(px[j], px[j])));
        float t0 = __fmaf_rn(px[j], m2x0, s);
        t0 = __fmaf_rn(py[j], m2y0, t0);
        t0 = __fmaf_rn(pz[j], m2z0, t0);
        m0[j] = __ballot(t0 <= th0);
        float t1 = __fmaf_rn(px[j], m2x1, s);
        t1 = __fmaf_rn(py[j], m2y1, t1);
        t1 = __fmaf_rn(pz[j], m2z1, t1);
        m1[j] = __ballot(t1 <= th1);
        any |= m0[j] | m1[j];
    }
    if (any) {
        #pragma unroll
        for (int j = 0; j < PPL; ++j) {
            if (m0[j]) {
                const float dx = __fadd_rn(px[j], -qx0);
                const float dy = __fadd_rn(py[j], -qy0);
                const float dz = __fadd_rn(pz[j], -qz0);
                const float d  = __fadd_rn(
                    __fadd_rn(__fmul_rn(dx, dx), __fmul_rn(dy, dy)),
                    __fmul_rn(dz, dz));
                insert_all<0>(d, pb + j, lane, ld, li, tau0, th0, qnm0);
            }
        }
        #pragma unroll
        for (int j = 0; j < PPL; ++j) {
            if (m1[j]) {
                const float dx = __fadd_rn(px[j], -qx1);
                const float dy = __fadd_rn(py[j], -qy1);
                const float dz = __fadd_rn(pz[j], -qz1);
                const float d  = __fadd_rn(
                    __fadd_rn(__fmul_rn(dx, dx), __fmul_rn(dy, dy)),
                    __fmul_rn(dz, dz));
                insert_all<1>(d, pb + j, lane, ld, li, tau1, th1, qnm1);
            }
        }
    }
}

__global__ __launch_bounds__(BLOCK) void knn2(const float* __restrict__ xyz,
                                              float* __restrict__ out_idx,
                                              float* __restrict__ out_pts)
{
    const int tid  = threadIdx.x;
    const int lane = tid & 63;
    const int wv   = tid >> 6;
    const int w    = blockIdx.x * WPB + wv;
    const int b    = w >> 10;
    const int pr   = w & 1023;
    const size_t base = (size_t)b * NPTS * 3;

    const int qp0 = pr << 5;
    const float qx0 = xyz[base + 3 * qp0 + 0];
    const float qy0 = xyz[base + 3 * qp0 + 1];
    const float qz0 = xyz[base + 3 * qp0 + 2];
    const float qx1 = xyz[base + 3 * qp0 + 48];
    const float qy1 = xyz[base + 3 * qp0 + 49];
    const float qz1 = xyz[base + 3 * qp0 + 50];

    const int g0 = b * NQ + (pr << 1);
    if (lane == 0) {
        out_pts[3 * g0 + 0] = qx0;
        out_pts[3 * g0 + 1] = qy0;
        out_pts[3 * g0 + 2] = qz0;
        out_pts[3 * g0 + 3] = qx1;
        out_pts[3 * g0 + 4] = qy1;
        out_pts[3 * g0 + 5] = qz1;
    }

    const float m2x0 = -2.0f * qx0, m2y0 = -2.0f * qy0, m2z0 = -2.0f * qz0;
    const float m2x1 = -2.0f * qx1, m2y1 = -2.0f * qy1, m2z1 = -2.0f * qz1;
    const float qnm0 = -(qx0 * qx0 + qy0 * qy0 + qz0 * qz0) + GATE_MARGIN;
    const float qnm1 = -(qx1 * qx1 + qy1 * qy1 + qz1 * qz1) + GATE_MARGIN;

    float ld = __builtin_inff();  int li = 0x7fffffff;
    float tau0 = __builtin_inff(), tau1 = __builtin_inff();
    float th0  = __builtin_inff(), th1  = __builtin_inff();

    const float4* lp = (const float4*)(xyz + base) + 6 * lane;

    float4 A[6], Bf[6];
    load6(A, lp);
    for (int k = 0; k < ITERS; k += 2) {
        load6(Bf, lp + 384);
        step2(A, (k << 9) + PPL * lane, lane,
              m2x0, m2y0, m2z0, m2x1, m2y1, m2z1,
              qx0, qy0, qz0, qx1, qy1, qz1,
              ld, li, tau0, tau1, th0, th1, qnm0, qnm1);
        if (k + 2 < ITERS)
            load6(A, lp + 768);
        step2(Bf, ((k + 1) << 9) + PPL * lane, lane,
              m2x0, m2y0, m2z0, m2x1, m2y1, m2z1,
              qx0, qy0, qz0, qx1, qy1, qz1,
              ld, li, tau0, tau1, th0, th1, qnm0, qnm1);
        lp += 768;
    }

    if (lane < 2 * KNN) {
        out_idx[(size_t)g0 * KNN + lane] = (float)li;
    }
}

extern "C" void kernel_launch(void* const* d_in, const int* in_sizes, int n_in,
                              void* d_out, int out_size, void* d_ws, size_t ws_size,
                              hipStream_t stream) {
    const float* xyz = (const float*)d_in[0];
    float* out = (float*)d_out;
    float* out_idx = out;                                 // NB*NQ*KNN floats
    float* out_pts = out + (size_t)NB * NQ * KNN;         // NB*NQ*3 floats

    const size_t ws_needed = (size_t)NB * NPTS * sizeof(float4);   // 2 MB
    if (d_ws != nullptr && ws_size >= ws_needed) {
        float4* wsp = (float4*)d_ws;
        repack_kernel<<<NB * NPTS / (4 * 256), 256, 0, stream>>>(xyz, wsp);
        knn1<<<NB * NQ / WPBA, BLOCKA, 0, stream>>>(wsp, out_idx, out_pts);
    } else {
        knn2<<<(NB * NQ / 2) / WPB, BLOCK, 0, stream>>>(xyz, out_idx, out_pts);
    }
}

// Round 11
// 229.355 us; speedup vs baseline: 1.3126x; 1.3126x over previous
//
#include <hip/hip_runtime.h>
#include <stdint.h>

// Problem constants: B=4, N=32768, K=16, nqueries=2048, stride=16.
// Geometry: one query PAIR per block (128 thr = 2 waves). Each wave scans
// HALF the stream (16384 pts) for both queries -> 8192 waves (8/SIMD).
// KEY vs the failed R7 split: the two waves EXCHANGE their running taus
// through LDS every step (no barriers; stale reads are conservative since
// tau only decreases). Each wave's gate threshold uses min(own, partner)
// tau, so inserts happen only for candidates beating the GLOBAL running
// 16th -> insert work returns to single-stream counts (no duplication).
// Gate: dot-product expansion, s=|p|^2 shared by both queries (11 ops/pt).
// Exact numpy-ordered recompute + exact insert for accepted lanes; exact
// rank-merge of the two sorted 16-lists at the end (distinct-key argument:
// filler (inf,maxidx) entries always rank >=16, never written).
#define NPTS  32768
#define NQ    2048
#define KNN   16
#define NB    4
#define BLOCK 128
#define PPL   8                     // points per lane per iteration
#define HALF  (NPTS / 2)            // 16384 points per wave
#define ITERS_H (HALF / (64 * PPL)) // 32
#define GATE_MARGIN 5e-4f

__device__ __forceinline__ int dpp_shr1_i(int x) {
    // row_shr:1 within 16-lane rows; row-start lane keeps old (bound_ctrl=0)
    return __builtin_amdgcn_update_dpp(x, x, 0x111, 0xf, 0xf, false);
}
__device__ __forceinline__ float dpp_shr1_f(float x) {
    return __int_as_float(dpp_shr1_i(__float_as_int(x)));
}
__device__ __forceinline__ float readlane_f(float x, int l) {
    return __int_as_float(__builtin_amdgcn_readlane(__float_as_int(x), l));
}

// Exact distributed top-16 for query T (0/1): sorted list (ascending by
// (dist,idx)) in lanes 16T..16T+15; lane 16T+15 holds this wave's exact
// threshold tau. d is the EXACT numpy distance. th = min(tau, ts) + qnm is
// the conservative gate threshold (ts = partner wave's tau, qnm = -|q|^2
// + margin).
template <int T>
__device__ __forceinline__ void insert_all(float d, int p, int lane,
                                           float& ld, int& li, float& tau,
                                           float& th, float qnm, float ts)
{
    unsigned long long rem = __ballot(d <= tau);
    while (rem) {
        const int srcl = __ffsll(rem) - 1;           // wave-uniform
        const float wd = readlane_f(d, srcl);
        const int   wi = __builtin_amdgcn_readlane(p, srcl);
        const bool less = (ld < wd) || (ld == wd && li < wi);
        const unsigned long long lm = __ballot(less);
        const int pos = __popc((unsigned)((lm >> (16 * T)) & 0xffffull));
        const float pld = dpp_shr1_f(ld);
        const int   pli = dpp_shr1_i(li);
        if ((lane >> 4) == T) {
            const int gl = lane & 15;
            if (gl == pos)      { ld = wd;  li = wi;  }
            else if (gl > pos)  { ld = pld; li = pli; }
        }
        tau = readlane_f(ld, 16 * T + 15);
        th  = fminf(tau, ts) + qnm;                  // shared-tau gate update
        rem &= rem - 1;
        if (rem) rem &= __ballot(d <= tau);          // re-gate survivors (exact)
    }
}

__device__ __forceinline__ void load6(float4 dst[6], const float4* p) {
    #pragma unroll
    for (int t = 0; t < 6; ++t) dst[t] = p[t];
}

// One 512-point step: 8 pts/lane; shared |p|^2 + per-query 3-fma gate;
// exact recompute + exact insert for accepted slots.
__device__ __forceinline__ void step2(const float4 c[6], int pb, int lane,
                                      float m2x0, float m2y0, float m2z0,
                                      float m2x1, float m2y1, float m2z1,
                                      float qx0, float qy0, float qz0,
                                      float qx1, float qy1, float qz1,
                                      float& ld, int& li,
                                      float& tau0, float& tau1,
                                      float& th0, float& th1,
                                      float qnm0, float qnm1,
                                      float ts0, float ts1)
{
    float px[PPL], py[PPL], pz[PPL];                 // pure register renames
    px[0] = c[0].x; py[0] = c[0].y; pz[0] = c[0].z;
    px[1] = c[0].w; py[1] = c[1].x; pz[1] = c[1].y;
    px[2] = c[1].z; py[2] = c[1].w; pz[2] = c[2].x;
    px[3] = c[2].y; py[3] = c[2].z; pz[3] = c[2].w;
    px[4] = c[3].x; py[4] = c[3].y; pz[4] = c[3].z;
    px[5] = c[3].w; py[5] = c[4].x; pz[5] = c[4].y;
    px[6] = c[4].z; py[6] = c[4].w; pz[6] = c[5].x;
    px[7] = c[5].y; py[7] = c[5].z; pz[7] = c[5].w;

    unsigned long long m0[PPL], m1[PPL], any = 0;
    #pragma unroll
    for (int j = 0; j < PPL; ++j) {                  // 8 independent chains
        const float s = __fmaf_rn(pz[j], pz[j],
                          __fmaf_rn(py[j], py[j], __fmul_rn(px[j], px[j])));
        float t0 = __fmaf_rn(px[j], m2x0, s);
        t0 = __fmaf_rn(py[j], m2y0, t0);
        t0 = __fmaf_rn(pz[j], m2z0, t0);
        m0[j] = __ballot(t0 <= th0);
        float t1 = __fmaf_rn(px[j], m2x1, s);
        t1 = __fmaf_rn(py[j], m2y1, t1);
        t1 = __fmaf_rn(pz[j], m2z1, t1);
        m1[j] = __ballot(t1 <= th1);
        any |= m0[j] | m1[j];
    }
    if (any) {
        #pragma unroll
        for (int j = 0; j < PPL; ++j) {
            if (m0[j]) {                             // exact numpy distance
                const float dx = __fadd_rn(px[j], -qx0);
                const float dy = __fadd_rn(py[j], -qy0);
                const float dz = __fadd_rn(pz[j], -qz0);
                const float d  = __fadd_rn(
                    __fadd_rn(__fmul_rn(dx, dx), __fmul_rn(dy, dy)),
                    __fmul_rn(dz, dz));
                insert_all<0>(d, pb + j, lane, ld, li, tau0, th0, qnm0, ts0);
            }
        }
        #pragma unroll
        for (int j = 0; j < PPL; ++j) {
            if (m1[j]) {
                const float dx = __fadd_rn(px[j], -qx1);
                const float dy = __fadd_rn(py[j], -qy1);
                const float dz = __fadd_rn(pz[j], -qz1);
                const float d  = __fadd_rn(
                    __fadd_rn(__fmul_rn(dx, dx), __fmul_rn(dy, dy)),
                    __fmul_rn(dz, dz));
                insert_all<1>(d, pb + j, lane, ld, li, tau1, th1, qnm1, ts1);
            }
        }
    }
}

// 4096 blocks x 2 waves = 8192 waves (8/SIMD if VGPR<=64; natural ~52).
// NO min-waves launch_bounds arg (its cap semantics forced VGPR 32/40 and
// spilled GBs in rounds 3-4).
__global__ __launch_bounds__(BLOCK) void knn_kernel(const float* __restrict__ xyz,
                                                    float* __restrict__ out_idx,
                                                    float* __restrict__ out_pts)
{
    const int tid  = threadIdx.x;
    const int lane = tid & 63;
    const int half = tid >> 6;               // which half of the point stream
    const int pair = blockIdx.x;             // query pair id in [0, 4096)
    const int b    = pair >> 10;
    const int pr   = pair & 1023;
    const size_t base = (size_t)b * NPTS * 3;

    const int qp0 = pr << 5;                 // stride-16 subsample
    const float qx0 = xyz[base + 3 * qp0 + 0];
    const float qy0 = xyz[base + 3 * qp0 + 1];
    const float qz0 = xyz[base + 3 * qp0 + 2];
    const float qx1 = xyz[base + 3 * qp0 + 48];
    const float qy1 = xyz[base + 3 * qp0 + 49];
    const float qz1 = xyz[base + 3 * qp0 + 50];

    const int g0 = b * NQ + (pr << 1);
    if (half == 0 && lane == 0) {
        out_pts[3 * g0 + 0] = qx0;
        out_pts[3 * g0 + 1] = qy0;
        out_pts[3 * g0 + 2] = qz0;
        out_pts[3 * g0 + 3] = qx1;
        out_pts[3 * g0 + 4] = qy1;
        out_pts[3 * g0 + 5] = qz1;
    }

    // Gate constants: m2* = -2q*, qnm = -|q|^2 + margin.
    const float m2x0 = -2.0f * qx0, m2y0 = -2.0f * qy0, m2z0 = -2.0f * qz0;
    const float m2x1 = -2.0f * qx1, m2y1 = -2.0f * qy1, m2z1 = -2.0f * qz1;
    const float qnm0 = -(qx0 * qx0 + qy0 * qy0 + qz0 * qz0) + GATE_MARGIN;
    const float qnm1 = -(qx1 * qx1 + qy1 * qy1 + qz1 * qz1) + GATE_MARGIN;

    // Cross-wave tau exchange buffer. Init both slots, one barrier, then
    // barrier-free: 32-bit LDS word reads see old-or-new (both safe, tau
    // monotonically decreases).
    __shared__ float stau[2][2];
    if (lane == 0) { stau[half][0] = __builtin_inff(); stau[half][1] = __builtin_inff(); }
    __syncthreads();

    float ld = __builtin_inff();  int li = 0x7fffffff;
    float tau0 = __builtin_inff(), tau1 = __builtin_inff();
    float th0  = __builtin_inff(), th1  = __builtin_inff();
    float ts0  = __builtin_inff(), ts1  = __builtin_inff();

    // Lane's stream within this wave's half: 8 consecutive points per iter.
    const int pbase = half * HALF;
    const float4* lp = (const float4*)(xyz + base) + half * (HALF * 3 / 4) + 6 * lane;

    float4 A[6], Bf[6];
    load6(A, lp);                                    // prologue
    for (int k = 0; k < ITERS_H; k += 2) {           // double-buffered pipeline
        load6(Bf, lp + 384);                         // prefetch iter k+1
        step2(A, pbase + (k << 9) + PPL * lane, lane,
              m2x0, m2y0, m2z0, m2x1, m2y1, m2z1,
              qx0, qy0, qz0, qx1, qy1, qz1,
              ld, li, tau0, tau1, th0, th1, qnm0, qnm1, ts0, ts1);
        // publish own taus, pull partner's; tighten gate thresholds
        if (lane == 0) { stau[half][0] = tau0; stau[half][1] = tau1; }
        ts0 = stau[half ^ 1][0];
        ts1 = stau[half ^ 1][1];
        th0 = fminf(tau0, ts0) + qnm0;
        th1 = fminf(tau1, ts1) + qnm1;
        if (k + 2 < ITERS_H)
            load6(A, lp + 768);                      // prefetch iter k+2
        step2(Bf, pbase + ((k + 1) << 9) + PPL * lane, lane,
              m2x0, m2y0, m2z0, m2x1, m2y1, m2z1,
              qx0, qy0, qz0, qx1, qy1, qz1,
              ld, li, tau0, tau1, th0, th1, qnm0, qnm1, ts0, ts1);
        if (lane == 0) { stau[half][0] = tau0; stau[half][1] = tau1; }
        ts0 = stau[half ^ 1][0];
        ts1 = stau[half ^ 1][1];
        th0 = fminf(tau0, ts0) + qnm0;
        th1 = fminf(tau1, ts1) + qnm1;
        lp += 768;
    }

    // ---- exact merge of the two halves' sorted top-16 lists (per query) ----
    // Key order is lexicographic (d, idx); real keys distinct => merged
    // position = own rank + #(strictly smaller in partner). Filler entries
    // (inf, maxidx) always land at pos>=16 (union holds >=16 real entries
    // because shared-tau pruning provably keeps every global-top-16 point).
    __shared__ float sd[2 * 32];
    __shared__ int   si[2 * 32];
    if (lane < 32) {
        sd[(half << 5) + lane] = ld;
        si[(half << 5) + lane] = li;
    }
    __syncthreads();
    if (lane < 32) {
        const int T  = lane >> 4;                    // query within pair
        const int r  = lane & 15;                    // rank in own list
        const int pb2 = ((half ^ 1) << 5) + (T << 4);
        int cnt = 0;
        #pragma unroll
        for (int t = 0; t < 16; ++t) {               // broadcast reads (free)
            const float od = sd[pb2 + t];
            const int   oi = si[pb2 + t];
            cnt += (od < ld || (od == ld && oi < li)) ? 1 : 0;
        }
        const int pos = r + cnt;
        if (pos < KNN)
            out_idx[((size_t)(g0 + T)) * KNN + pos] = (float)li;
    }
}

extern "C" void kernel_launch(void* const* d_in, const int* in_sizes, int n_in,
                              void* d_out, int out_size, void* d_ws, size_t ws_size,
                              hipStream_t stream) {
    const float* xyz = (const float*)d_in[0];
    float* out = (float*)d_out;
    float* out_idx = out;                                 // NB*NQ*KNN floats
    float* out_pts = out + (size_t)NB * NQ * KNN;         // NB*NQ*3 floats

    const int blocks = NB * NQ / 2;                       // 4096 pairs
    knn_kernel<<<blocks, BLOCK, 0, stream>>>(xyz, out_idx, out_pts);
}

// Round 14
// 182.716 us; speedup vs baseline: 1.6477x; 1.2553x over previous
//
#include <hip/hip_runtime.h>
#include <stdint.h>

// Problem constants: B=4, N=32768, K=16, nqueries=2048, stride=16.
// Geometry (R9, best measured 144us): 2 queries per wave, full 32K stream,
// 256-thr blocks, 4096 waves. Gate: dot-product expansion, s=|p|^2 shared
// by both queries (11 ops/pt/pair); conservative margin; accepted lanes
// re-verified with the EXACT numpy-ordered distance (bit-exact results).
//
// NEW vs R9: 3-buffer software pipeline (A,B,C), prefetch distance ~2 full
// steps (~260 cyc) to cover the ~200-cyc L2 hit latency. R9's 2-buffer loop
// issued each load only ~1 step (~130 cyc) before use -> every step stalled
// on vmcnt; VALUBusy was 66%. 64 iters = 3x21 + 1 epilogue; tail loads
// guarded (wave-uniform branch) so no OOB reads past the batch.
#define NPTS  32768
#define NQ    2048
#define KNN   16
#define NB    4
#define BLOCK 256
#define WPB   4               // waves per block; 2 queries per wave
#define PPL   8               // points per lane per iteration
#define ITERS (NPTS / (64 * PPL))   // 64
#define GATE_MARGIN 5e-4f

__device__ __forceinline__ int dpp_shr1_i(int x) {
    // row_shr:1 within 16-lane rows; row-start lane keeps old (bound_ctrl=0)
    return __builtin_amdgcn_update_dpp(x, x, 0x111, 0xf, 0xf, false);
}
__device__ __forceinline__ float dpp_shr1_f(float x) {
    return __int_as_float(dpp_shr1_i(__float_as_int(x)));
}
__device__ __forceinline__ float readlane_f(float x, int l) {
    return __int_as_float(__builtin_amdgcn_readlane(__float_as_int(x), l));
}

// Exact distributed top-16 for query T (0/1): sorted list (ascending by
// (dist,idx)) in lanes 16T..16T+15; lane 16T+15 holds the exact threshold
// tau. d is the EXACT numpy distance. th = tau + qnm is the conservative
// dot-product-gate threshold (qnm = -|q|^2 + margin).
template <int T>
__device__ __forceinline__ void insert_all(float d, int p, int lane,
                                           float& ld, int& li, float& tau,
                                           float& th, float qnm)
{
    unsigned long long rem = __ballot(d <= tau);
    while (rem) {
        const int srcl = __ffsll(rem) - 1;           // wave-uniform
        const float wd = readlane_f(d, srcl);
        const int   wi = __builtin_amdgcn_readlane(p, srcl);
        const bool less = (ld < wd) || (ld == wd && li < wi);
        const unsigned long long lm = __ballot(less);
        const int pos = __popc((unsigned)((lm >> (16 * T)) & 0xffffull));
        const float pld = dpp_shr1_f(ld);
        const int   pli = dpp_shr1_i(li);
        if ((lane >> 4) == T) {
            const int gl = lane & 15;
            if (gl == pos)      { ld = wd;  li = wi;  }
            else if (gl > pos)  { ld = pld; li = pli; }
        }
        tau = readlane_f(ld, 16 * T + 15);
        th  = tau + qnm;                             // gate threshold update
        rem &= rem - 1;
        if (rem) rem &= __ballot(d <= tau);          // re-gate survivors (exact)
    }
}

__device__ __forceinline__ void load6(float4 dst[6], const float4* p) {
    #pragma unroll
    for (int t = 0; t < 6; ++t) dst[t] = p[t];
}

// One 512-point step: 8 pts/lane; shared |p|^2 + per-query 3-fma gate;
// exact recompute + exact insert for accepted slots.
__device__ __forceinline__ void step2(const float4 c[6], int pb, int lane,
                                      float m2x0, float m2y0, float m2z0,
                                      float m2x1, float m2y1, float m2z1,
                                      float qx0, float qy0, float qz0,
                                      float qx1, float qy1, float qz1,
                                      float& ld, int& li,
                                      float& tau0, float& tau1,
                                      float& th0, float& th1,
                                      float qnm0, float qnm1)
{
    float px[PPL], py[PPL], pz[PPL];                 // pure register renames
    px[0] = c[0].x; py[0] = c[0].y; pz[0] = c[0].z;
    px[1] = c[0].w; py[1] = c[1].x; pz[1] = c[1].y;
    px[2] = c[1].z; py[2] = c[1].w; pz[2] = c[2].x;
    px[3] = c[2].y; py[3] = c[2].z; pz[3] = c[2].w;
    px[4] = c[3].x; py[4] = c[3].y; pz[4] = c[3].z;
    px[5] = c[3].w; py[5] = c[4].x; pz[5] = c[4].y;
    px[6] = c[4].z; py[6] = c[4].w; pz[6] = c[5].x;
    px[7] = c[5].y; py[7] = c[5].z; pz[7] = c[5].w;

    unsigned long long m0[PPL], m1[PPL], any = 0;
    #pragma unroll
    for (int j = 0; j < PPL; ++j) {                  // 8 independent chains
        const float s = __fmaf_rn(pz[j], pz[j],
                          __fmaf_rn(py[j], py[j], __fmul_rn(px[j], px[j])));
        float t0 = __fmaf_rn(px[j], m2x0, s);
        t0 = __fmaf_rn(py[j], m2y0, t0);
        t0 = __fmaf_rn(pz[j], m2z0, t0);
        m0[j] = __ballot(t0 <= th0);
        float t1 = __fmaf_rn(px[j], m2x1, s);
        t1 = __fmaf_rn(py[j], m2y1, t1);
        t1 = __fmaf_rn(pz[j], m2z1, t1);
        m1[j] = __ballot(t1 <= th1);
        any |= m0[j] | m1[j];
    }
    if (any) {
        #pragma unroll
        for (int j = 0; j < PPL; ++j) {
            if (m0[j]) {                             // exact numpy distance
                const float dx = __fadd_rn(px[j], -qx0);
                const float dy = __fadd_rn(py[j], -qy0);
                const float dz = __fadd_rn(pz[j], -qz0);
                const float d  = __fadd_rn(
                    __fadd_rn(__fmul_rn(dx, dx), __fmul_rn(dy, dy)),
                    __fmul_rn(dz, dz));
                insert_all<0>(d, pb + j, lane, ld, li, tau0, th0, qnm0);
            }
        }
        #pragma unroll
        for (int j = 0; j < PPL; ++j) {
            if (m1[j]) {
                const float dx = __fadd_rn(px[j], -qx1);
                const float dy = __fadd_rn(py[j], -qy1);
                const float dz = __fadd_rn(pz[j], -qz1);
                const float d  = __fadd_rn(
                    __fadd_rn(__fmul_rn(dx, dx), __fmul_rn(dy, dy)),
                    __fmul_rn(dz, dz));
                insert_all<1>(d, pb + j, lane, ld, li, tau1, th1, qnm1);
            }
        }
    }
}

// 1024 blocks x 4 waves = 4096 waves. launch_bounds(256,4) caps VGPR at
// 128 (proven no-spill combo from R1: cap stays ABOVE natural demand ~110;
// the disasters were caps BELOW demand). 3 buffers x 24 VGPR = 72 + ~40
// live scalars ~= 110.
__global__ __launch_bounds__(BLOCK, 4) void knn_kernel(const float* __restrict__ xyz,
                                                       float* __restrict__ out_idx,
                                                       float* __restrict__ out_pts)
{
    const int tid  = threadIdx.x;
    const int lane = tid & 63;
    const int wv   = tid >> 6;
    const int w    = blockIdx.x * WPB + wv;          // wave id in [0, 4096)
    const int b    = w >> 10;
    const int pr   = w & 1023;                       // query pair
    const size_t base = (size_t)b * NPTS * 3;

    const int qp0 = pr << 5;                         // stride-16 subsample
    const float qx0 = xyz[base + 3 * qp0 + 0];
    const float qy0 = xyz[base + 3 * qp0 + 1];
    const float qz0 = xyz[base + 3 * qp0 + 2];
    const float qx1 = xyz[base + 3 * qp0 + 48];
    const float qy1 = xyz[base + 3 * qp0 + 49];
    const float qz1 = xyz[base + 3 * qp0 + 50];

    const int g0 = b * NQ + (pr << 1);
    if (lane == 0) {
        out_pts[3 * g0 + 0] = qx0;
        out_pts[3 * g0 + 1] = qy0;
        out_pts[3 * g0 + 2] = qz0;
        out_pts[3 * g0 + 3] = qx1;
        out_pts[3 * g0 + 4] = qy1;
        out_pts[3 * g0 + 5] = qz1;
    }

    // Gate constants: m2* = -2q*, qnm = -|q|^2 + margin.
    const float m2x0 = -2.0f * qx0, m2y0 = -2.0f * qy0, m2z0 = -2.0f * qz0;
    const float m2x1 = -2.0f * qx1, m2y1 = -2.0f * qy1, m2z1 = -2.0f * qz1;
    const float qnm0 = -(qx0 * qx0 + qy0 * qy0 + qz0 * qz0) + GATE_MARGIN;
    const float qnm1 = -(qx1 * qx1 + qy1 * qy1 + qz1 * qz1) + GATE_MARGIN;

    float ld = __builtin_inff();  int li = 0x7fffffff;
    float tau0 = __builtin_inff(), tau1 = __builtin_inff();
    float th0  = __builtin_inff(), th1  = __builtin_inff();

    // Lane's stream: 8 consecutive points (6 float4) per iteration.
    // Iteration i's lane data lives at lp0 + 384*i.
    const float4* lp0 = (const float4*)(xyz + base) + 6 * lane;

    // 3-stage software pipeline: buffer X holds iteration (3t + stage).
    float4 A[6], Bf[6], Cf[6];
    load6(A,  lp0);                                  // iter 0
    load6(Bf, lp0 + 384);                            // iter 1
    load6(Cf, lp0 + 768);                            // iter 2
    const float4* ld_ptr = lp0 + 3 * 384;            // next load: iter 3
    int pb = PPL * lane;                             // point base, iter 0

    for (int it = 0; it < 21; ++it) {                // iters 0..62
        step2(A, pb, lane,
              m2x0, m2y0, m2z0, m2x1, m2y1, m2z1,
              qx0, qy0, qz0, qx1, qy1, qz1,
              ld, li, tau0, tau1, th0, th1, qnm0, qnm1);
        pb += 512;
        load6(A, ld_ptr);  ld_ptr += 384;            // iter 3it+3 (<=63: valid)
        step2(Bf, pb, lane,
              m2x0, m2y0, m2z0, m2x1, m2y1, m2z1,
              qx0, qy0, qz0, qx1, qy1, qz1,
              ld, li, tau0, tau1, th0, th1, qnm0, qnm1);
        pb += 512;
        if (it < 20) load6(Bf, ld_ptr);              // iter 3it+4 (guard OOB)
        ld_ptr += 384;
        step2(Cf, pb, lane,
              m2x0, m2y0, m2z0, m2x1, m2y1, m2z1,
              qx0, qy0, qz0, qx1, qy1, qz1,
              ld, li, tau0, tau1, th0, th1, qnm0, qnm1);
        pb += 512;
        if (it < 20) load6(Cf, ld_ptr);              // iter 3it+5 (guard OOB)
        ld_ptr += 384;
    }
    // epilogue: iter 63 (loaded into A during it=20)
    step2(A, pb, lane,
          m2x0, m2y0, m2z0, m2x1, m2y1, m2z1,
          qx0, qy0, qz0, qx1, qy1, qz1,
          ld, li, tau0, tau1, th0, th1, qnm0, qnm1);

    // lanes 0..15: q0 ranks 0..15; lanes 16..31: q1 ranks (g1 = g0+1)
    if (lane < 2 * KNN) {
        out_idx[(size_t)g0 * KNN + lane] = (float)li;
    }
}

extern "C" void kernel_launch(void* const* d_in, const int* in_sizes, int n_in,
                              void* d_out, int out_size, void* d_ws, size_t ws_size,
                              hipStream_t stream) {
    const float* xyz = (const float*)d_in[0];
    float* out = (float*)d_out;
    float* out_idx = out;                                 // NB*NQ*KNN floats
    float* out_pts = out + (size_t)NB * NQ * KNN;         // NB*NQ*3 floats

    const int blocks = (NB * NQ / 2) / WPB;               // 1024
    knn_kernel<<<blocks, BLOCK, 0, stream>>>(xyz, out_idx, out_pts);
}